// Round 3
// baseline (2674.758 us; speedup 1.0000x reference)
//
#include <hip/hip_runtime.h>

// SelfAttention: x[8,256,64,64] fp32, W[256,256] fp32.
// R3: 64 q-rows/wave, 2-wave blocks, global_load_lds staging with
// pre-swizzled per-lane sources (zero staging regs), fixed V swizzle.
// ws: xT[b][N][C] bf16 | xC[b][C][N] bf16 | ctxT[b][N][C] bf16 (unnorm) |
//     Wb bf16 | Ld f32 [b][N]

typedef __attribute__((ext_vector_type(8))) short short8;
typedef __attribute__((ext_vector_type(4))) float floatx4;
typedef __attribute__((ext_vector_type(16))) float floatx16;
typedef __attribute__((ext_vector_type(4))) int intx4;

#define N_TOK 4096
#define C_DIM 256
#define JT 32
#define NT (N_TOK / JT)

typedef const __attribute__((address_space(1))) unsigned int g_uint;
typedef __attribute__((address_space(3))) unsigned int lds_uint;

__device__ __forceinline__ void gll16(const void* g, void* l) {
  __builtin_amdgcn_global_load_lds((g_uint*)g, (lds_uint*)l, 16, 0, 0);
}

__device__ __forceinline__ unsigned short f2bf(float f) {
  unsigned int u = __builtin_bit_cast(unsigned int, f);
  u += 0x7fffu + ((u >> 16) & 1u);
  return (unsigned short)(u >> 16);
}

__device__ __forceinline__ floatx16 mfma32(short8 a, short8 b, floatx16 c) {
  return __builtin_amdgcn_mfma_f32_32x32x16_bf16(a, b, c, 0, 0, 0);
}
__device__ __forceinline__ floatx4 mfma16(short8 a, short8 b, floatx4 c) {
  return __builtin_amdgcn_mfma_f32_16x16x32_bf16(a, b, c, 0, 0, 0);
}
__device__ __forceinline__ unsigned cvtpk(float lo, float hi) {
  unsigned d;
  asm("v_cvt_pk_bf16_f32 %0, %1, %2" : "=v"(d) : "v"(lo), "v"(hi));
  return d;
}
__device__ __forceinline__ void swap32(unsigned& a, unsigned& b) {
  asm("v_permlane32_swap_b32 %0, %1" : "+v"(a), "+v"(b));
}

// ---- K1a: x[b][c][i] fp32 -> xT[b][i][c] bf16 and xC[b][c][i] bf16 ----
__global__ __launch_bounds__(256) void transpose_conv(
    const float* __restrict__ x, unsigned short* __restrict__ xT,
    unsigned short* __restrict__ xC) {
  __shared__ float tile[32][33];
  const int b = blockIdx.z;
  const int i0 = blockIdx.x * 32, c0 = blockIdx.y * 32;
  const int tx = threadIdx.x & 31, ty = threadIdx.x >> 5;
  const float* xb = x + (size_t)b * C_DIM * N_TOK;
#pragma unroll
  for (int p = 0; p < 4; ++p) {
    int c = c0 + ty + p * 8;
    float v = xb[(size_t)c * N_TOK + i0 + tx];
    tile[ty + p * 8][tx] = v;
    xC[((size_t)b * C_DIM + c) * N_TOK + i0 + tx] = f2bf(v);
  }
  __syncthreads();
#pragma unroll
  for (int p = 0; p < 4; ++p) {
    int i = i0 + ty + p * 8;
    xT[((size_t)b * N_TOK + i) * C_DIM + c0 + tx] = f2bf(tile[tx][ty + p * 8]);
  }
}

// ---- K1b: W fp32 -> bf16 ----
__global__ __launch_bounds__(256) void wconv(const float* __restrict__ W,
                                             unsigned short* __restrict__ Wb) {
  int idx = blockIdx.x * 256 + threadIdx.x;
  Wb[idx] = f2bf(W[idx]);
}

// ---- K2: flash attention. grid 256 (=32 qtiles x 8 batches), 128 thr ----
// 2 waves x 64 q-rows. Wave 0 stages K, wave 1 stages V (global_load_lds).
__global__ __launch_bounds__(128, 1) void attn_kernel(
    const unsigned short* __restrict__ xT, const unsigned short* __restrict__ xC,
    unsigned short* __restrict__ ctxT, float* __restrict__ Ld) {
  const int bid = blockIdx.x;
  const int b = bid & 7;  // batch == XCD -> per-batch L2 locality
  const int qt = bid >> 3;
  const int tid = threadIdx.x;
  const int lane = tid & 63;
  const int w = tid >> 6;
  const int l31 = lane & 31;
  const int h = lane >> 5;
  const unsigned short* xTb = xT + (size_t)b * N_TOK * C_DIM;
  const unsigned short* xCb = xC + (size_t)b * N_TOK * C_DIM;
  const int qb = qt * 128 + w * 64;

  __shared__ char lds[2][32768];  // per buf: K 16KB [32j][256c] swz, V 16KB [256c][32j] swz

  // staging: LDS slot o = i*1024 + lane*16 (linear, gll requirement).
  // K layout: elem (j,c16) at (j*512 + c16*16) ^ ((j&31)<<4)
  //   -> slot o holds j = 2i + e (e=lane>>5), c16 = (lane&31) ^ (2i+e)
  // V layout: elem (c,jc) at (c*64 + jc*16) ^ (((c>>3)&3)<<4)
  //   -> slot o holds c = 16i + (lane>>2), jc = (lane&3) ^ ((2i + (lane>>5))&3)
  const int e5 = lane >> 5;
  const int Ak = (lane & 31) ^ e5;       // K source helper
  const int q2 = lane >> 2;              // V source helper
  const int z5 = lane >> 5;

  auto STAGE = [&](int t) {
    char* dst = &lds[t & 1][w << 14];
    if (w == 0) {
      const char* src = (const char*)xTb + (size_t)t * 16384;
#pragma unroll
      for (int i = 0; i < 16; ++i) {
        int off = i * 1024 + e5 * 512 + ((Ak ^ (2 * i)) << 4);
        gll16(src + off, dst + i * 1024);
      }
    } else {
      const char* src = (const char*)xCb + (size_t)t * 64;
#pragma unroll
      for (int i = 0; i < 16; ++i) {
        int jcs = (lane & 3) ^ ((2 * (i & 1) + z5) & 3);
        int off = i * 131072 + q2 * 8192 + jcs * 16;
        gll16(src + off, dst + i * 1024);
      }
    }
  };

  // Q fragments (B-operand): rows qb+l31 (q0) and qb+32+l31 (q1)
  short8 q0[16], q1[16];
  {
    const unsigned short* qp0 = xTb + (size_t)(qb + l31) * C_DIM + h * 8;
    const unsigned short* qp1 = qp0 + 32 * C_DIM;
#pragma unroll
    for (int ks = 0; ks < 16; ++ks) {
      q0[ks] = *(const short8*)(qp0 + ks * 16);
      q1[ks] = *(const short8*)(qp1 + ks * 16);
    }
  }

  floatx16 accL[8], accH[8];
#pragma unroll
  for (int ct = 0; ct < 8; ++ct)
#pragma unroll
    for (int r = 0; r < 16; ++r) { accL[ct][r] = 0.f; accH[ct][r] = 0.f; }
  float m0 = -1e30f, m1 = -1e30f, ls0 = 0.f, ls1 = 0.f;
  const float SC = 0.09016844005556021f;  // log2(e)/16

  STAGE(0);

  for (int t = 0; t < NT; ++t) {
    __syncthreads();  // drains own vmcnt (tile t staged) + prior reads done
    if (t + 1 < NT) STAGE(t + 1);
    const char* Kb = lds[t & 1];
    const char* Vb = lds[t & 1] + 16384;

    // S^T = mfma(K, Q): s0 -> q-rows l31 (+qb), s1 -> q-rows 32+l31
    floatx16 s0, s1;
#pragma unroll
    for (int r = 0; r < 16; ++r) { s0[r] = 0.f; s1[r] = 0.f; }
#pragma unroll
    for (int ks = 0; ks < 16; ++ks) {
      short8 kf = *(const short8*)(Kb + ((l31 * 512 + ks * 32 + h * 16) ^ (l31 << 4)));
      s0 = mfma32(kf, q0[ks], s0);
      s1 = mfma32(kf, q1[ks], s1);
    }

    // online softmax, both row-halves; lane owns rows l31 and 32+l31
    float mx0 = s0[0], mx1 = s1[0];
#pragma unroll
    for (int r = 1; r < 16; ++r) { mx0 = fmaxf(mx0, s0[r]); mx1 = fmaxf(mx1, s1[r]); }
    mx0 = fmaxf(mx0, __shfl_xor(mx0, 32));
    mx1 = fmaxf(mx1, __shfl_xor(mx1, 32));
    float pm0 = mx0 * SC, pm1 = mx1 * SC;
    bool need = __any((pm0 > m0 + 8.0f) || (pm1 > m1 + 8.0f)) != 0;  // defer-max
    float mn0 = need ? fmaxf(m0, pm0) : m0;
    float mn1 = need ? fmaxf(m1, pm1) : m1;
    float al0 = need ? exp2f(m0 - mn0) : 1.0f;
    float al1 = need ? exp2f(m1 - mn1) : 1.0f;
    m0 = mn0; m1 = mn1;
    float rs0 = 0.f, rs1 = 0.f;
#pragma unroll
    for (int r = 0; r < 16; ++r) {
      s0[r] = exp2f(s0[r] * SC - mn0); rs0 += s0[r];
      s1[r] = exp2f(s1[r] * SC - mn1); rs1 += s1[r];
    }
    rs0 += __shfl_xor(rs0, 32);
    rs1 += __shfl_xor(rs1, 32);
    ls0 = ls0 * al0 + rs0;
    ls1 = ls1 * al1 + rs1;
    if (need) {  // wave-uniform, rare
#pragma unroll
      for (int r = 0; r < 16; ++r) {
        int cr = (r & 3) + 8 * (r >> 2) + 4 * h;
        float a0 = __shfl(al0, cr);
        float a1 = __shfl(al1, cr);
#pragma unroll
        for (int ct = 0; ct < 8; ++ct) { accL[ct][r] *= a0; accH[ct][r] *= a1; }
      }
    }

    // P^T -> PV A-fragments in-register (cvt_pk + permlane32_swap), per half
    unsigned pk[8];
#pragma unroll
    for (int pi = 0; pi < 8; ++pi) pk[pi] = cvtpk(s0[2 * pi], s0[2 * pi + 1]);
    swap32(pk[0], pk[2]); swap32(pk[1], pk[3]);
    swap32(pk[4], pk[6]); swap32(pk[5], pk[7]);
    intx4 a0v = {(int)pk[0], (int)pk[1], (int)pk[2], (int)pk[3]};
    intx4 a1v = {(int)pk[4], (int)pk[5], (int)pk[6], (int)pk[7]};
    short8 pa0 = __builtin_bit_cast(short8, a0v);
    short8 pa1 = __builtin_bit_cast(short8, a1v);
#pragma unroll
    for (int pi = 0; pi < 8; ++pi) pk[pi] = cvtpk(s1[2 * pi], s1[2 * pi + 1]);
    swap32(pk[0], pk[2]); swap32(pk[1], pk[3]);
    swap32(pk[4], pk[6]); swap32(pk[5], pk[7]);
    intx4 b0v = {(int)pk[0], (int)pk[1], (int)pk[2], (int)pk[3]};
    intx4 b1v = {(int)pk[4], (int)pk[5], (int)pk[6], (int)pk[7]};
    short8 pb0 = __builtin_bit_cast(short8, b0v);
    short8 pb1 = __builtin_bit_cast(short8, b1v);

    // O += P V: V read once, feeds both row-halves
#pragma unroll
    for (int ct = 0; ct < 8; ++ct) {
      int c = ct * 32 + l31;
      int swz = ((l31 >> 3) & 3) << 4;
      short8 v0 = *(const short8*)(Vb + ((c * 64 + h * 16) ^ swz));
      short8 v1 = *(const short8*)(Vb + ((c * 64 + (2 + h) * 16) ^ swz));
      accL[ct] = mfma32(pa0, v0, accL[ct]);
      accL[ct] = mfma32(pa1, v1, accL[ct]);
      accH[ct] = mfma32(pb0, v0, accH[ct]);
      accH[ct] = mfma32(pb1, v1, accH[ct]);
    }
  }

  // epilogue: store unnormalized O (bf16) + row sums l (f32)
  Ld[(size_t)b * N_TOK + qb + h * 32 + l31] = h ? ls1 : ls0;
  unsigned short* cb = ctxT + ((size_t)b * N_TOK + qb) * C_DIM;
#pragma unroll
  for (int r = 0; r < 16; ++r) {
    int ri = (r & 3) + 8 * (r >> 2) + 4 * h;
#pragma unroll
    for (int ct = 0; ct < 8; ++ct) {
      cb[(size_t)ri * C_DIM + ct * 32 + l31] = f2bf(accL[ct][r]);
      cb[(size_t)(ri + 32) * C_DIM + ct * 32 + l31] = f2bf(accH[ct][r]);
    }
  }
}

// ---- K3: out[b][o][i] = (1/l[i]) * sum_c W[o][c] * ctxT[i][c] ----
__global__ __launch_bounds__(256) void outgemm(
    const unsigned short* __restrict__ ctxT, const unsigned short* __restrict__ Wb,
    const float* __restrict__ Ld, float* __restrict__ out) {
  const int bid = blockIdx.x;
  const int b = bid & 7;
  const int it = bid >> 3;
  const int lane = threadIdx.x & 63;
  const int w = threadIdx.x >> 6;
  const int ibase = it * 64 + w * 16;
  const int l15 = lane & 15, lhi = lane >> 4;
  const unsigned short* cbase = ctxT + (size_t)b * N_TOK * C_DIM;

  float li[4];
#pragma unroll
  for (int r = 0; r < 4; ++r)
    li[r] = 1.0f / Ld[(size_t)b * N_TOK + ibase + lhi * 4 + r];

  floatx4 acc[16];
#pragma unroll
  for (int i = 0; i < 16; ++i) acc[i] = (floatx4){0.f, 0.f, 0.f, 0.f};

#pragma unroll
  for (int ks = 0; ks < 8; ++ks) {
    short8 a = *(const short8*)(cbase + (size_t)(ibase + l15) * C_DIM + ks * 32 + lhi * 8);
#pragma unroll
    for (int ob = 0; ob < 16; ++ob) {
      short8 bw = *(const short8*)(Wb + (size_t)(ob * 16 + l15) * C_DIM + ks * 32 + lhi * 8);
      acc[ob] = mfma16(a, bw, acc[ob]);
    }
  }
  float* outb = out + (size_t)b * C_DIM * N_TOK;
#pragma unroll
  for (int ob = 0; ob < 16; ++ob) {
#pragma unroll
    for (int r = 0; r < 4; ++r) {
      int o = ob * 16 + l15;
      int i = ibase + lhi * 4 + r;
      outb[(size_t)o * N_TOK + i] = acc[ob][r] * li[r];
    }
  }
}

extern "C" void kernel_launch(void* const* d_in, const int* in_sizes, int n_in,
                              void* d_out, int out_size, void* d_ws, size_t ws_size,
                              hipStream_t stream) {
  const float* x = (const float*)d_in[0];
  const float* W = (const float*)d_in[1];
  float* out = (float*)d_out;
  char* ws = (char*)d_ws;
  const size_t SZ = (size_t)8 * N_TOK * C_DIM * 2;  // 16 MB per bf16 tensor
  unsigned short* xT = (unsigned short*)(ws);
  unsigned short* xC = (unsigned short*)(ws + SZ);
  unsigned short* ctxT = (unsigned short*)(ws + 2 * SZ);
  unsigned short* Wb = (unsigned short*)(ws + 3 * SZ);
  float* Ld = (float*)(ws + 3 * SZ + C_DIM * C_DIM * 2);

  hipLaunchKernelGGL(transpose_conv, dim3(N_TOK / 32, C_DIM / 32, 8), dim3(256), 0,
                     stream, x, xT, xC);
  hipLaunchKernelGGL(wconv, dim3((C_DIM * C_DIM) / 256), dim3(256), 0, stream, W, Wb);
  hipLaunchKernelGGL(attn_kernel, dim3(256), dim3(128), 0, stream, xT, xC, ctxT, Ld);
  hipLaunchKernelGGL(outgemm, dim3(512), dim3(256), 0, stream, ctxT, Wb, Ld, out);
}

// Round 4
// 267.251 us; speedup vs baseline: 10.0084x; 10.0084x over previous
//
#include <hip/hip_runtime.h>

// SelfAttention: x[8,256,64,64] fp32, W[256,256] fp32.
// R4: 4 waves x 32 q-rows, JT=64 double-buffered LDS (2x64KB),
// global_load_lds staging w/ inverse-swizzled sources, conflict-free
// V layout [256c][64j] (128B rows, (c&7) XOR), m97 pipeline pattern.
// ws: xT[b][N][C] bf16 | xC[b][C][N] bf16 | ctxT[b][N][C] bf16 (unnorm) |
//     Wb bf16 | Ld f32 [b][N]

typedef __attribute__((ext_vector_type(8))) short short8;
typedef __attribute__((ext_vector_type(4))) float floatx4;
typedef __attribute__((ext_vector_type(16))) float floatx16;
typedef __attribute__((ext_vector_type(4))) int intx4;

#define N_TOK 4096
#define C_DIM 256
#define JT 64
#define NT (N_TOK / JT)

typedef const __attribute__((address_space(1))) unsigned int g_uint;
typedef __attribute__((address_space(3))) unsigned int lds_uint;

__device__ __forceinline__ void gll16(const void* g, void* l) {
  __builtin_amdgcn_global_load_lds((g_uint*)g, (lds_uint*)l, 16, 0, 0);
}

__device__ __forceinline__ unsigned short f2bf(float f) {
  unsigned int u = __builtin_bit_cast(unsigned int, f);
  u += 0x7fffu + ((u >> 16) & 1u);
  return (unsigned short)(u >> 16);
}

__device__ __forceinline__ floatx16 mfma32(short8 a, short8 b, floatx16 c) {
  return __builtin_amdgcn_mfma_f32_32x32x16_bf16(a, b, c, 0, 0, 0);
}
__device__ __forceinline__ floatx4 mfma16(short8 a, short8 b, floatx4 c) {
  return __builtin_amdgcn_mfma_f32_16x16x32_bf16(a, b, c, 0, 0, 0);
}
__device__ __forceinline__ unsigned cvtpk(float lo, float hi) {
  unsigned d;
  asm("v_cvt_pk_bf16_f32 %0, %1, %2" : "=v"(d) : "v"(lo), "v"(hi));
  return d;
}
__device__ __forceinline__ void swap32(unsigned& a, unsigned& b) {
  asm("v_permlane32_swap_b32 %0, %1" : "+v"(a), "+v"(b));
}

// ---- K1a: x[b][c][i] fp32 -> xT[b][i][c] bf16 and xC[b][c][i] bf16 ----
__global__ __launch_bounds__(256) void transpose_conv(
    const float* __restrict__ x, unsigned short* __restrict__ xT,
    unsigned short* __restrict__ xC) {
  __shared__ float tile[32][33];
  const int b = blockIdx.z;
  const int i0 = blockIdx.x * 32, c0 = blockIdx.y * 32;
  const int tx = threadIdx.x & 31, ty = threadIdx.x >> 5;
  const float* xb = x + (size_t)b * C_DIM * N_TOK;
#pragma unroll
  for (int p = 0; p < 4; ++p) {
    int c = c0 + ty + p * 8;
    float v = xb[(size_t)c * N_TOK + i0 + tx];
    tile[ty + p * 8][tx] = v;
    xC[((size_t)b * C_DIM + c) * N_TOK + i0 + tx] = f2bf(v);
  }
  __syncthreads();
#pragma unroll
  for (int p = 0; p < 4; ++p) {
    int i = i0 + ty + p * 8;
    xT[((size_t)b * N_TOK + i) * C_DIM + c0 + tx] = f2bf(tile[tx][ty + p * 8]);
  }
}

// ---- K1b: W fp32 -> bf16 ----
__global__ __launch_bounds__(256) void wconv(const float* __restrict__ W,
                                             unsigned short* __restrict__ Wb) {
  int idx = blockIdx.x * 256 + threadIdx.x;
  Wb[idx] = f2bf(W[idx]);
}

// ---- K2: flash attention. grid 256 (=32 qtiles x 8 batches), 256 thr ----
// 4 waves x 32 q-rows = 128 q-rows/block. JT=64 K/V tiles, double-buffered.
// LDS buffer layout (64KB each):
//   K [0,32KB):  elem(j,c16)  at byte  j*512 + (c16 ^ (j&31))*16
//   V [32KB,64KB): elem(c,jc) at byte  c*128 + (jc  ^ (c&7 ))*16   (jc = j/8)
__global__ __launch_bounds__(256, 1) void attn_kernel(
    const unsigned short* __restrict__ xT, const unsigned short* __restrict__ xC,
    unsigned short* __restrict__ ctxT, float* __restrict__ Ld) {
  const int bid = blockIdx.x;
  const int b = bid & 7;  // batch == XCD -> per-batch L2 locality (4MB slab fits L2)
  const int qt = bid >> 3;
  const int tid = threadIdx.x;
  const int lane = tid & 63;
  const int wv = tid >> 6;
  const int l31 = lane & 31;
  const int h = lane >> 5;
  const unsigned short* xTb = xT + (size_t)b * N_TOK * C_DIM;
  const unsigned short* xCb = xC + (size_t)b * N_TOK * C_DIM;
  const int qb = qt * 128 + wv * 32;

  __shared__ char lds[2][65536];  // 128 KB total

  // --- staging: linear LDS slots via global_load_lds, inverse-swizzled src.
  // slot s = i*4096 + wv*1024 + lane*16  (lds_ptr uniform per wave; HW adds lane*16)
  // K (i 0..7):  j = s>>9 = i*8 + wv*2 + (lane>>5); c16 = (lane&31) ^ (j&31)
  // V (i 0..7):  c = i*32 + wv*8 + (lane>>3);       jc  = (lane&7) ^ ((lane>>3)&7)
  const char* xTc = (const char*)xTb;
  const char* xCc = (const char*)xCb;
  auto STAGE = [&](int t, int sel) {
    char* buf = lds[sel];
    {
      char* dstw = buf + wv * 1024;
      size_t tbase = (size_t)t * 32768;  // t*64 rows * 512 B
#pragma unroll
      for (int i = 0; i < 8; ++i) {
        int j = i * 8 + wv * 2 + (lane >> 5);
        int c16 = (lane & 31) ^ (j & 31);
        gll16(xTc + tbase + (size_t)j * 512 + c16 * 16, dstw + i * 4096);
      }
    }
    {
      char* dstw = buf + 32768 + wv * 1024;
      int jc = (lane & 7) ^ ((lane >> 3) & 7);
      size_t tbase = (size_t)t * 128 + jc * 16;  // within xC row (8192 B)
#pragma unroll
      for (int i = 0; i < 8; ++i) {
        int c = i * 32 + wv * 8 + (lane >> 3);
        gll16(xCc + (size_t)c * 8192 + tbase, dstw + i * 4096);
      }
    }
  };

  // Q B-fragments: rows qb+l31, k = ks*16 + h*8 + t
  short8 q[16];
  {
    const unsigned short* qp = xTb + (size_t)(qb + l31) * C_DIM + h * 8;
#pragma unroll
    for (int ks = 0; ks < 16; ++ks) q[ks] = *(const short8*)(qp + ks * 16);
  }

  floatx16 acc[8];
#pragma unroll
  for (int ct = 0; ct < 8; ++ct)
#pragma unroll
    for (int r = 0; r < 16; ++r) acc[ct][r] = 0.f;
  float m = -1e30f, lsum = 0.f;
  const float SC = 0.09016844005556021f;  // log2(e)/16

  STAGE(0, 0);

  for (int t = 0; t < NT; ++t) {
    __syncthreads();  // vmcnt(0) drain: tile t staged; prev-buf reads done
    if (t + 1 < NT) STAGE(t + 1, (t + 1) & 1);
    const char* Kb = lds[t & 1];
    const char* Vb = lds[t & 1] + 32768;

    // S^T = mfma(K, Q): s0 -> j 0..31, s1 -> j 32..63, lane owns q-row l31
    floatx16 s0, s1;
#pragma unroll
    for (int r = 0; r < 16; ++r) { s0[r] = 0.f; s1[r] = 0.f; }
#pragma unroll
    for (int ks = 0; ks < 16; ++ks) {
      int cs = ks * 32 + h * 16;
      short8 k0 = *(const short8*)(Kb + (l31 * 512 + (cs ^ (l31 << 4))));
      short8 k1 = *(const short8*)(Kb + ((32 + l31) * 512 + (cs ^ (l31 << 4))));
      s0 = mfma32(k0, q[ks], s0);
      s1 = mfma32(k1, q[ks], s1);
    }

    // online softmax over 64 j; lane's q-row i = l31 (dup in h)
    float mx = fmaxf(s0[0], s1[0]);
#pragma unroll
    for (int r = 1; r < 16; ++r) mx = fmaxf(mx, fmaxf(s0[r], s1[r]));
    mx = fmaxf(mx, __shfl_xor(mx, 32));
    float pm = mx * SC;
    bool need = __any(pm > m + 8.0f) != 0;  // defer-max (T13)
    float mn = need ? fmaxf(m, pm) : m;
    float al = need ? exp2f(m - mn) : 1.0f;
    m = mn;
    float rs = 0.f;
#pragma unroll
    for (int r = 0; r < 16; ++r) {
      s0[r] = exp2f(s0[r] * SC - mn); rs += s0[r];
      s1[r] = exp2f(s1[r] * SC - mn); rs += s1[r];
    }
    rs += __shfl_xor(rs, 32);
    lsum = lsum * al + rs;
    if (need) {  // wave-uniform, rare after warmup
#pragma unroll
      for (int r = 0; r < 16; ++r) {
        float ar = __shfl(al, (r & 3) + 8 * (r >> 2) + 4 * h);
#pragma unroll
        for (int ct = 0; ct < 8; ++ct) acc[ct][r] *= ar;
      }
    }

    // P^T -> PV A-fragments in-register (cvt_pk + permlane32_swap)
    unsigned pk[8];
#pragma unroll
    for (int pi = 0; pi < 8; ++pi) pk[pi] = cvtpk(s0[2 * pi], s0[2 * pi + 1]);
    swap32(pk[0], pk[2]); swap32(pk[1], pk[3]);
    swap32(pk[4], pk[6]); swap32(pk[5], pk[7]);
    intx4 a0v = {(int)pk[0], (int)pk[1], (int)pk[2], (int)pk[3]};
    intx4 a1v = {(int)pk[4], (int)pk[5], (int)pk[6], (int)pk[7]};
    short8 pa0 = __builtin_bit_cast(short8, a0v);  // k = j 0..15
    short8 pa1 = __builtin_bit_cast(short8, a1v);  // k = j 16..31
#pragma unroll
    for (int pi = 0; pi < 8; ++pi) pk[pi] = cvtpk(s1[2 * pi], s1[2 * pi + 1]);
    swap32(pk[0], pk[2]); swap32(pk[1], pk[3]);
    swap32(pk[4], pk[6]); swap32(pk[5], pk[7]);
    intx4 b0v = {(int)pk[0], (int)pk[1], (int)pk[2], (int)pk[3]};
    intx4 b1v = {(int)pk[4], (int)pk[5], (int)pk[6], (int)pk[7]};
    short8 pb0 = __builtin_bit_cast(short8, b0v);  // k = j 32..47
    short8 pb1 = __builtin_bit_cast(short8, b1v);  // k = j 48..63

    // O[i][c] += P[i][j] V[j][c]; V-frag (k-step ks): row c, bytes (ks*2+h)*16
#pragma unroll
    for (int ct = 0; ct < 8; ++ct) {
      int c = ct * 32 + l31;
      int base = c * 128;
      int swz = (c & 7) << 4;
      short8 v0 = *(const short8*)(Vb + (base + ((h * 16) ^ swz)));
      short8 v1 = *(const short8*)(Vb + (base + ((32 + h * 16) ^ swz)));
      short8 v2 = *(const short8*)(Vb + (base + ((64 + h * 16) ^ swz)));
      short8 v3 = *(const short8*)(Vb + (base + ((96 + h * 16) ^ swz)));
      acc[ct] = mfma32(pa0, v0, acc[ct]);
      acc[ct] = mfma32(pa1, v1, acc[ct]);
      acc[ct] = mfma32(pb0, v2, acc[ct]);
      acc[ct] = mfma32(pb1, v3, acc[ct]);
    }
  }

  // epilogue: store unnormalized O (bf16) + row sums l (f32)
  if (lane < 32) Ld[(size_t)b * N_TOK + qb + l31] = lsum;
  unsigned short* cb = ctxT + ((size_t)b * N_TOK + qb) * C_DIM;
#pragma unroll
  for (int r = 0; r < 16; ++r) {
    int ri = (r & 3) + 8 * (r >> 2) + 4 * h;
#pragma unroll
    for (int ct = 0; ct < 8; ++ct)
      cb[(size_t)ri * C_DIM + ct * 32 + l31] = f2bf(acc[ct][r]);
  }
}

// ---- K3: out[b][o][i] = (1/l[i]) * sum_c W[o][c] * ctxT[i][c] ----
__global__ __launch_bounds__(256) void outgemm(
    const unsigned short* __restrict__ ctxT, const unsigned short* __restrict__ Wb,
    const float* __restrict__ Ld, float* __restrict__ out) {
  const int bid = blockIdx.x;
  const int b = bid & 7;
  const int it = bid >> 3;
  const int lane = threadIdx.x & 63;
  const int w = threadIdx.x >> 6;
  const int ibase = it * 64 + w * 16;
  const int l15 = lane & 15, lhi = lane >> 4;
  const unsigned short* cbase = ctxT + (size_t)b * N_TOK * C_DIM;

  float li[4];
#pragma unroll
  for (int r = 0; r < 4; ++r)
    li[r] = 1.0f / Ld[(size_t)b * N_TOK + ibase + lhi * 4 + r];

  floatx4 acc[16];
#pragma unroll
  for (int i = 0; i < 16; ++i) acc[i] = (floatx4){0.f, 0.f, 0.f, 0.f};

#pragma unroll
  for (int ks = 0; ks < 8; ++ks) {
    short8 a = *(const short8*)(cbase + (size_t)(ibase + l15) * C_DIM + ks * 32 + lhi * 8);
#pragma unroll
    for (int ob = 0; ob < 16; ++ob) {
      short8 bw = *(const short8*)(Wb + (size_t)(ob * 16 + l15) * C_DIM + ks * 32 + lhi * 8);
      acc[ob] = mfma16(a, bw, acc[ob]);
    }
  }
  float* outb = out + (size_t)b * C_DIM * N_TOK;
#pragma unroll
  for (int ob = 0; ob < 16; ++ob) {
#pragma unroll
    for (int r = 0; r < 4; ++r) {
      int o = ob * 16 + l15;
      int i = ibase + lhi * 4 + r;
      outb[(size_t)o * N_TOK + i] = acc[ob][r] * li[r];
    }
  }
}

extern "C" void kernel_launch(void* const* d_in, const int* in_sizes, int n_in,
                              void* d_out, int out_size, void* d_ws, size_t ws_size,
                              hipStream_t stream) {
  const float* x = (const float*)d_in[0];
  const float* W = (const float*)d_in[1];
  float* out = (float*)d_out;
  char* ws = (char*)d_ws;
  const size_t SZ = (size_t)8 * N_TOK * C_DIM * 2;  // 16 MB per bf16 tensor
  unsigned short* xT = (unsigned short*)(ws);
  unsigned short* xC = (unsigned short*)(ws + SZ);
  unsigned short* ctxT = (unsigned short*)(ws + 2 * SZ);
  unsigned short* Wb = (unsigned short*)(ws + 3 * SZ);
  float* Ld = (float*)(ws + 3 * SZ + C_DIM * C_DIM * 2);

  hipLaunchKernelGGL(transpose_conv, dim3(N_TOK / 32, C_DIM / 32, 8), dim3(256), 0,
                     stream, x, xT, xC);
  hipLaunchKernelGGL(wconv, dim3((C_DIM * C_DIM) / 256), dim3(256), 0, stream, W, Wb);
  hipLaunchKernelGGL(attn_kernel, dim3(256), dim3(256), 0, stream, xT, xC, ctxT, Ld);
  hipLaunchKernelGGL(outgemm, dim3(512), dim3(256), 0, stream, ctxT, Wb, Ld, out);
}

// Round 5
// 236.012 us; speedup vs baseline: 11.3332x; 1.1324x over previous
//
#include <hip/hip_runtime.h>

// SelfAttention: x[8,256,64,64] fp32, W[256,256] fp32.
// R5: split-K flash attention. 512 blocks = 8 batch x 32 qtile x 2 j-halves.
// Block: 4 waves x 32 q-rows, JT=32 double-buffered LDS (64KB -> 2 blocks/CU,
// 2 waves/SIMD TLP). Partials (O bf16, m, l f32) merged in outgemm.
// ws: xT[b][N][C] | xC[b][C][N] | ctxP[2][b][N][C] | Wb | ML[2][b][N] float2

typedef __attribute__((ext_vector_type(8))) short short8;
typedef __attribute__((ext_vector_type(4))) float floatx4;
typedef __attribute__((ext_vector_type(16))) float floatx16;
typedef __attribute__((ext_vector_type(4))) int intx4;

#define N_TOK 4096
#define C_DIM 256
#define JT 32
#define NT 64  // 2048 / JT per half

typedef const __attribute__((address_space(1))) unsigned int g_uint;
typedef __attribute__((address_space(3))) unsigned int lds_uint;

__device__ __forceinline__ void gll16(const void* g, void* l) {
  __builtin_amdgcn_global_load_lds((g_uint*)g, (lds_uint*)l, 16, 0, 0);
}

__device__ __forceinline__ unsigned short f2bf(float f) {
  unsigned int u = __builtin_bit_cast(unsigned int, f);
  u += 0x7fffu + ((u >> 16) & 1u);
  return (unsigned short)(u >> 16);
}
__device__ __forceinline__ float bf2f(unsigned short v) {
  return __builtin_bit_cast(float, (unsigned int)v << 16);
}

__device__ __forceinline__ floatx16 mfma32(short8 a, short8 b, floatx16 c) {
  return __builtin_amdgcn_mfma_f32_32x32x16_bf16(a, b, c, 0, 0, 0);
}
__device__ __forceinline__ floatx4 mfma16(short8 a, short8 b, floatx4 c) {
  return __builtin_amdgcn_mfma_f32_16x16x32_bf16(a, b, c, 0, 0, 0);
}
__device__ __forceinline__ unsigned cvtpk(float lo, float hi) {
  unsigned d;
  asm("v_cvt_pk_bf16_f32 %0, %1, %2" : "=v"(d) : "v"(lo), "v"(hi));
  return d;
}
__device__ __forceinline__ void swap32(unsigned& a, unsigned& b) {
  asm("v_permlane32_swap_b32 %0, %1" : "+v"(a), "+v"(b));
}

// ---- K1a: x[b][c][i] fp32 -> xT[b][i][c] bf16 and xC[b][c][i] bf16 ----
__global__ __launch_bounds__(256) void transpose_conv(
    const float* __restrict__ x, unsigned short* __restrict__ xT,
    unsigned short* __restrict__ xC) {
  __shared__ float tile[32][33];
  const int b = blockIdx.z;
  const int i0 = blockIdx.x * 32, c0 = blockIdx.y * 32;
  const int tx = threadIdx.x & 31, ty = threadIdx.x >> 5;
  const float* xb = x + (size_t)b * C_DIM * N_TOK;
#pragma unroll
  for (int p = 0; p < 4; ++p) {
    int c = c0 + ty + p * 8;
    float v = xb[(size_t)c * N_TOK + i0 + tx];
    tile[ty + p * 8][tx] = v;
    xC[((size_t)b * C_DIM + c) * N_TOK + i0 + tx] = f2bf(v);
  }
  __syncthreads();
#pragma unroll
  for (int p = 0; p < 4; ++p) {
    int i = i0 + ty + p * 8;
    xT[((size_t)b * N_TOK + i) * C_DIM + c0 + tx] = f2bf(tile[tx][ty + p * 8]);
  }
}

// ---- K1b: W fp32 -> bf16 ----
__global__ __launch_bounds__(256) void wconv(const float* __restrict__ W,
                                             unsigned short* __restrict__ Wb) {
  int idx = blockIdx.x * 256 + threadIdx.x;
  Wb[idx] = f2bf(W[idx]);
}

// ---- K2: split-K flash attention. grid 512, 256 thr, 2 blocks/CU ----
// LDS buffer (32KB each, x2):
//   K [0,16KB):   elem(j,c16) at j*512 + ((c16 ^ (j&7))<<4)        j=0..31
//   V [16KB,32KB): paired rows [128r][128B]: elem(c,jc) at
//                  (c>>1)*128 + (((jc | ((c&1)<<2)) ^ ((c>>1)&7))<<4), jc=0..3
__global__ __launch_bounds__(256, 2) void attn_kernel(
    const unsigned short* __restrict__ xT, const unsigned short* __restrict__ xC,
    unsigned short* __restrict__ ctxP, float2* __restrict__ MLd) {
  const int bid = blockIdx.x;
  const int b = bid & 7;           // batch == XCD -> L2 locality
  const int qt = (bid >> 3) & 31;  // q-tile (128 rows)
  const int g = bid >> 8;          // j-half
  const int tid = threadIdx.x;
  const int lane = tid & 63;
  const int wv = tid >> 6;
  const int l31 = lane & 31;
  const int h = lane >> 5;
  const unsigned short* xTb = xT + (size_t)b * N_TOK * C_DIM;
  const unsigned short* xCb = xC + (size_t)b * N_TOK * C_DIM;
  const char* xTc = (const char*)xTb;
  const char* xCc = (const char*)xCb;
  const int qb = qt * 128 + wv * 32;

  __shared__ char lds[2][32768];

  // staging: linear slots o = i*4096 + wv*1024 + lane*16, inverse-swizzled src
  auto STAGE = [&](int t, int sel) {
    size_t jb = (size_t)(g * 2048 + t * 32);
    char* Kd = lds[sel] + wv * 1024;
#pragma unroll
    for (int i = 0; i < 4; ++i) {
      int j = i * 8 + wv * 2 + (lane >> 5);
      int c16 = (lane & 31) ^ (j & 7);
      gll16(xTc + (jb + j) * 512 + c16 * 16, Kd + i * 4096);
    }
    char* Vd = lds[sel] + 16384 + wv * 1024;
#pragma unroll
    for (int i = 0; i < 4; ++i) {
      int r = i * 32 + wv * 8 + (lane >> 3);
      int e = (lane & 7) ^ (r & 7);
      int c = 2 * r + (e >> 2);
      gll16(xCc + (size_t)c * 8192 + jb * 2 + (e & 3) * 16, Vd + i * 4096);
    }
  };

  // Q B-fragments: rows qb+l31, k = ks*16 + h*8 + t
  short8 q[16];
  {
    const unsigned short* qp = xTb + (size_t)(qb + l31) * C_DIM + h * 8;
#pragma unroll
    for (int ks = 0; ks < 16; ++ks) q[ks] = *(const short8*)(qp + ks * 16);
  }

  floatx16 acc[8];
#pragma unroll
  for (int ct = 0; ct < 8; ++ct)
#pragma unroll
    for (int r = 0; r < 16; ++r) acc[ct][r] = 0.f;
  float m = -1e30f, lsum = 0.f;
  const float SC = 0.09016844005556021f;  // log2(e)/16

  STAGE(0, 0);

  for (int t = 0; t < NT; ++t) {
    __syncthreads();  // tile t staged (vmcnt drain); prev-buf reads done
    if (t + 1 < NT) STAGE(t + 1, (t + 1) & 1);
    const char* Kb = lds[t & 1];
    const char* Vb = lds[t & 1] + 16384;

    // S^T = mfma(K, Q); lane owns q-row l31 (dup in h)
    floatx16 s;
#pragma unroll
    for (int r = 0; r < 16; ++r) s[r] = 0.f;
    __builtin_amdgcn_s_setprio(1);
#pragma unroll
    for (int ks = 0; ks < 16; ++ks) {
      short8 kf = *(const short8*)(Kb + l31 * 512 + (((2 * ks + h) ^ (l31 & 7)) << 4));
      s = mfma32(kf, q[ks], s);
    }
    __builtin_amdgcn_s_setprio(0);

    // online softmax over 32 j
    float mx = s[0];
#pragma unroll
    for (int r = 1; r < 16; ++r) mx = fmaxf(mx, s[r]);
    mx = fmaxf(mx, __shfl_xor(mx, 32));
    float pm = mx * SC;
    bool need = __any(pm > m + 8.0f) != 0;  // defer-max (T13)
    float mn = need ? fmaxf(m, pm) : m;
    float al = need ? exp2f(m - mn) : 1.0f;
    m = mn;
    float rsum = 0.f;
#pragma unroll
    for (int r = 0; r < 16; ++r) {
      s[r] = exp2f(s[r] * SC - mn);
      rsum += s[r];
    }
    rsum += __shfl_xor(rsum, 32);
    lsum = lsum * al + rsum;
    if (need) {  // wave-uniform, rare after warmup
#pragma unroll
      for (int r = 0; r < 16; ++r) {
        float ar = __shfl(al, (r & 3) + 8 * (r >> 2) + 4 * h);
#pragma unroll
        for (int ct = 0; ct < 8; ++ct) acc[ct][r] *= ar;
      }
    }

    // P^T -> PV A-fragments in-register (cvt_pk + permlane32_swap)
    unsigned pk[8];
#pragma unroll
    for (int pi = 0; pi < 8; ++pi) pk[pi] = cvtpk(s[2 * pi], s[2 * pi + 1]);
    swap32(pk[0], pk[2]); swap32(pk[1], pk[3]);
    swap32(pk[4], pk[6]); swap32(pk[5], pk[7]);
    intx4 a0v = {(int)pk[0], (int)pk[1], (int)pk[2], (int)pk[3]};
    intx4 a1v = {(int)pk[4], (int)pk[5], (int)pk[6], (int)pk[7]};
    short8 pa0 = __builtin_bit_cast(short8, a0v);  // k = j 0..15
    short8 pa1 = __builtin_bit_cast(short8, a1v);  // k = j 16..31

    // O[i][c] += P[i][j] V[j][c]
    __builtin_amdgcn_s_setprio(1);
#pragma unroll
    for (int ct = 0; ct < 8; ++ct) {
      int c = ct * 32 + l31;
      int r = c >> 1;
      int pb = (c & 1) << 2;
      int r7 = r & 7;
      short8 v0 = *(const short8*)(Vb + r * 128 + (((h | pb) ^ r7) << 4));
      short8 v1 = *(const short8*)(Vb + r * 128 + ((((2 + h) | pb) ^ r7) << 4));
      acc[ct] = mfma32(pa0, v0, acc[ct]);
      acc[ct] = mfma32(pa1, v1, acc[ct]);
    }
    __builtin_amdgcn_s_setprio(0);
  }

  // epilogue: store partial O (bf16, unnormalized) + (m, l)
  if (h == 0) {
    float2 ml; ml.x = m; ml.y = lsum;
    MLd[((size_t)g * 8 + b) * N_TOK + qb + l31] = ml;
  }
  unsigned short* cb = ctxP + (((size_t)g * 8 + b) * N_TOK + qb) * C_DIM;
#pragma unroll
  for (int r = 0; r < 16; ++r) {
    int ri = (r & 3) + 8 * (r >> 2) + 4 * h;
#pragma unroll
    for (int ct = 0; ct < 8; ++ct)
      cb[(size_t)ri * C_DIM + ct * 32 + l31] = f2bf(acc[ct][r]);
  }
}

// ---- K3: merge halves + out[b][o][i] = (1/l) sum_c W[o][c] ctx[i][c] ----
__global__ __launch_bounds__(256) void outgemm(
    const unsigned short* __restrict__ ctxP, const unsigned short* __restrict__ Wb,
    const float2* __restrict__ MLd, float* __restrict__ out) {
  const int bid = blockIdx.x;
  const int b = bid & 7;
  const int it = bid >> 3;
  const int lane = threadIdx.x & 63;
  const int w = threadIdx.x >> 6;
  const int ibase = it * 64 + w * 16;
  const int l15 = lane & 15, lhi = lane >> 4;
  const unsigned short* c0base = ctxP + (size_t)b * N_TOK * C_DIM;
  const unsigned short* c1base = ctxP + (size_t)(8 + b) * N_TOK * C_DIM;
  const float2* ml0b = MLd + (size_t)b * N_TOK;
  const float2* ml1b = MLd + (size_t)(8 + b) * N_TOK;

  // A-row merge weights (row ia = ibase + l15)
  const int ia = ibase + l15;
  float2 ma = ml0b[ia], mb = ml1b[ia];
  float Ma = fmaxf(ma.x, mb.x);
  float w0 = exp2f(ma.x - Ma), w1 = exp2f(mb.x - Ma);

  // store-row denominators (rows ibase + lhi*4 + r)
  float rden[4];
#pragma unroll
  for (int r = 0; r < 4; ++r) {
    int is = ibase + lhi * 4 + r;
    float2 s0 = ml0b[is], s1 = ml1b[is];
    float Ms = fmaxf(s0.x, s1.x);
    rden[r] = 1.0f / (s0.y * exp2f(s0.x - Ms) + s1.y * exp2f(s1.x - Ms));
  }

  floatx4 acc[16];
#pragma unroll
  for (int i = 0; i < 16; ++i) acc[i] = (floatx4){0.f, 0.f, 0.f, 0.f};

#pragma unroll
  for (int ks = 0; ks < 8; ++ks) {
    short8 o0 = *(const short8*)(c0base + (size_t)ia * C_DIM + ks * 32 + lhi * 8);
    short8 o1 = *(const short8*)(c1base + (size_t)ia * C_DIM + ks * 32 + lhi * 8);
    short8 am;
#pragma unroll
    for (int e = 0; e < 8; ++e)
      am[e] = (short)f2bf(w0 * bf2f((unsigned short)o0[e]) +
                          w1 * bf2f((unsigned short)o1[e]));
#pragma unroll
    for (int ob = 0; ob < 16; ++ob) {
      short8 bw = *(const short8*)(Wb + (size_t)(ob * 16 + l15) * C_DIM + ks * 32 + lhi * 8);
      acc[ob] = mfma16(am, bw, acc[ob]);
    }
  }
  float* outb = out + (size_t)b * C_DIM * N_TOK;
#pragma unroll
  for (int ob = 0; ob < 16; ++ob) {
#pragma unroll
    for (int r = 0; r < 4; ++r) {
      int o = ob * 16 + l15;
      int i = ibase + lhi * 4 + r;
      outb[(size_t)o * N_TOK + i] = acc[ob][r] * rden[r];
    }
  }
}

extern "C" void kernel_launch(void* const* d_in, const int* in_sizes, int n_in,
                              void* d_out, int out_size, void* d_ws, size_t ws_size,
                              hipStream_t stream) {
  const float* x = (const float*)d_in[0];
  const float* W = (const float*)d_in[1];
  float* out = (float*)d_out;
  char* ws = (char*)d_ws;
  const size_t SZ = (size_t)8 * N_TOK * C_DIM * 2;  // 16 MB per bf16 tensor
  unsigned short* xT = (unsigned short*)(ws);
  unsigned short* xC = (unsigned short*)(ws + SZ);
  unsigned short* ctxP = (unsigned short*)(ws + 2 * SZ);          // 32 MB (2 halves)
  unsigned short* Wb = (unsigned short*)(ws + 4 * SZ);            // 128 KB
  float2* MLd = (float2*)(ws + 4 * SZ + C_DIM * C_DIM * 2);       // 512 KB

  hipLaunchKernelGGL(transpose_conv, dim3(N_TOK / 32, C_DIM / 32, 8), dim3(256), 0,
                     stream, x, xT, xC);
  hipLaunchKernelGGL(wconv, dim3((C_DIM * C_DIM) / 256), dim3(256), 0, stream, W, Wb);
  hipLaunchKernelGGL(attn_kernel, dim3(512), dim3(256), 0, stream, xT, xC, ctxP, MLd);
  hipLaunchKernelGGL(outgemm, dim3(512), dim3(256), 0, stream, ctxP, Wb, MLd, out);
}